// Round 1
// baseline (13183.067 us; speedup 1.0000x reference)
//
#include <hip/hip_runtime.h>

#define TT 256         // time steps
#define VV 5000        // vocab
#define NC4 1250       // VV/4 float4 chunks per row
#define BEAMW 16
#define WASR 0.7f
#define WLM 0.3f
#define SOS_TOK 1
#define CAP 512

// ws float offsets
#define OFF_LMM   0                  // lm row max            [5000]
#define OFF_LMLS  5000               // lm row log-sum-exp    [5000]
#define OFF_AM    10000              // asr row max           [256]
#define OFF_ALS   10256              // asr row logS          [256]
#define OFF_AW    10752              // 0.7*asr_lp            [256*5000]
#define WS_NEED_FLOATS (OFF_AW + TT*VV)

// ---------------- prep: row max / logsumexp (+ optional Aw materialization) ----------
__global__ __launch_bounds__(256) void prep_kernel(
    const float* __restrict__ asr, const float* __restrict__ lm,
    float* __restrict__ ws, int write_A)
{
  __shared__ float sm[8];
  const int row = blockIdx.x;
  const bool is_lm = (row < VV);
  const int t = row - VV;
  const float* src = is_lm ? (lm + (size_t)row * VV) : (asr + (size_t)t * VV);
  const float4* s4 = (const float4*)src;

  float4 x[5];
  float m = -INFINITY;
#pragma unroll
  for (int k = 0; k < 5; ++k) {
    int c = (int)threadIdx.x + 256 * k;
    if (c < NC4) {
      x[k] = s4[c];
      m = fmaxf(m, fmaxf(fmaxf(x[k].x, x[k].y), fmaxf(x[k].z, x[k].w)));
    }
  }
  // block max
#pragma unroll
  for (int j = 1; j < 64; j <<= 1) m = fmaxf(m, __shfl_xor(m, j, 64));
  if ((threadIdx.x & 63) == 0) sm[threadIdx.x >> 6] = m;
  __syncthreads();
  m = fmaxf(fmaxf(sm[0], sm[1]), fmaxf(sm[2], sm[3]));
  __syncthreads();

  float ssum = 0.f;
#pragma unroll
  for (int k = 0; k < 5; ++k) {
    int c = (int)threadIdx.x + 256 * k;
    if (c < NC4) {
      ssum += expf(x[k].x - m);
      ssum += expf(x[k].y - m);
      ssum += expf(x[k].z - m);
      ssum += expf(x[k].w - m);
    }
  }
#pragma unroll
  for (int j = 1; j < 64; j <<= 1) ssum += __shfl_xor(ssum, j, 64);
  if ((threadIdx.x & 63) == 0) sm[4 + (threadIdx.x >> 6)] = ssum;
  __syncthreads();
  ssum = (sm[4] + sm[5]) + (sm[6] + sm[7]);
  const float logS = logf(ssum);

  if (is_lm) {
    if (threadIdx.x == 0) { ws[OFF_LMM + row] = m; ws[OFF_LMLS + row] = logS; }
  } else {
    if (threadIdx.x == 0) { ws[OFF_AM + t] = m; ws[OFF_ALS + t] = logS; }
    if (write_A) {
      float4* A4 = (float4*)(ws + OFF_AW + (size_t)t * VV);
#pragma unroll
      for (int k = 0; k < 5; ++k) {
        int c = (int)threadIdx.x + 256 * k;
        if (c < NC4) {
          float4 a;
          a.x = __fmul_rn(WASR, __fsub_rn(__fsub_rn(x[k].x, m), logS));
          a.y = __fmul_rn(WASR, __fsub_rn(__fsub_rn(x[k].y, m), logS));
          a.z = __fmul_rn(WASR, __fsub_rn(__fsub_rn(x[k].z, m), logS));
          a.w = __fmul_rn(WASR, __fsub_rn(__fsub_rn(x[k].w, m), logS));
          A4[c] = a;
        }
      }
    }
  }
}

// ---------------- persistent beam-search kernel: 1 block, 1024 threads, wave=row ------
__global__ __launch_bounds__(1024, 4) void beam_kernel(
    const float* __restrict__ asr, const float* __restrict__ lm,
    const float* __restrict__ ws, float* __restrict__ out, int ws_big)
{
  __shared__ float s_scores[BEAMW];
  __shared__ int   s_last[BEAMW];
  __shared__ float s_lmm[BEAMW], s_lmls[BEAMW];
  __shared__ float s_tau[BEAMW];
  __shared__ float s_bufval[CAP];
  __shared__ int   s_bufidx[CAP];
  __shared__ int   s_cnt;
  __shared__ unsigned short s_toks[TT * BEAMW];
  __shared__ unsigned char  s_bps[TT * BEAMW];

  const int tid  = (int)threadIdx.x;
  const int lane = tid & 63;
  const int w    = tid >> 6;          // wave index == hypothesis row

  if (tid < BEAMW) {
    s_scores[tid] = (tid == 0) ? 0.0f : -1e30f;
    s_last[tid]   = SOS_TOK;
    s_lmm[tid]    = ws[OFF_LMM + SOS_TOK];
    s_lmls[tid]   = ws[OFF_LMLS + SOS_TOK];
  }
  if (tid == 0) s_cnt = 0;
  __syncthreads();

  for (int t = 0; t < TT; ++t) {
    const float s   = s_scores[w];
    const float mB  = s_lmm[w];
    const float lsB = s_lmls[w];
    const int lastb = s_last[w];
    const float4* __restrict__ L4p = (const float4*)(lm + (size_t)lastb * VV);
    const float4* __restrict__ A4p;
    float am = 0.f, als = 0.f;
    if (ws_big) {
      A4p = (const float4*)(ws + OFF_AW + (size_t)t * VV);
    } else {
      A4p = (const float4*)(asr + (size_t)t * VV);
      am  = ws[OFF_AM + t];
      als = ws[OFF_ALS + t];
    }

    // Phase A: compute all candidate values for this row; keep per-chunk maxima.
    float chm[20];
    float rowm = -INFINITY;
#pragma unroll
    for (int k = 0; k < 20; ++k) {
      int c = lane + 64 * k;
      bool ok = (c < NC4);
      int cc = ok ? c : 0;
      float4 A4 = A4p[cc];
      float4 L4 = L4p[cc];
      float ax, ay, az, aw_;
      if (ws_big) { ax = A4.x; ay = A4.y; az = A4.z; aw_ = A4.w; }
      else {
        ax  = __fmul_rn(WASR, __fsub_rn(__fsub_rn(A4.x, am), als));
        ay  = __fmul_rn(WASR, __fsub_rn(__fsub_rn(A4.y, am), als));
        az  = __fmul_rn(WASR, __fsub_rn(__fsub_rn(A4.z, am), als));
        aw_ = __fmul_rn(WASR, __fsub_rn(__fsub_rn(A4.w, am), als));
      }
      float px = __fmul_rn(WLM, __fsub_rn(__fsub_rn(L4.x, mB), lsB));
      float py = __fmul_rn(WLM, __fsub_rn(__fsub_rn(L4.y, mB), lsB));
      float pz = __fmul_rn(WLM, __fsub_rn(__fsub_rn(L4.z, mB), lsB));
      float pw = __fmul_rn(WLM, __fsub_rn(__fsub_rn(L4.w, mB), lsB));
      float vx = __fadd_rn(__fadd_rn(s, ax),  px);
      float vy = __fadd_rn(__fadd_rn(s, ay),  py);
      float vz = __fadd_rn(__fadd_rn(s, az),  pz);
      float vw = __fadd_rn(__fadd_rn(s, aw_), pw);
      float cm = fmaxf(fmaxf(vx, vy), fmaxf(vz, vw));
      if (!ok) cm = -INFINITY;
      chm[k] = cm;
      rowm = fmaxf(rowm, cm);
    }

    // Phase A2: bitonic sort of 64 lane maxima (descending). 16th largest = valid row tau.
    {
      float v = rowm;
#pragma unroll
      for (int kk = 2; kk <= 64; kk <<= 1) {
#pragma unroll
        for (int j = kk >> 1; j > 0; j >>= 1) {
          float o = __shfl_xor(v, j, 64);
          bool keepMax = (((lane & kk) == 0) == ((lane & j) == 0));
          v = keepMax ? fmaxf(v, o) : fminf(v, o);
        }
      }
      if (lane == 15) s_tau[w] = v;   // 16th largest lane-max of this row
    }
    if (tid == 0) s_cnt = 0;
    __syncthreads();

    // Global tau = max over rows of per-row tau  (>=16 elements >= tau guaranteed).
    float tg = s_tau[lane & 15];
#pragma unroll
    for (int j = 1; j <= 8; j <<= 1) tg = fmaxf(tg, __shfl_xor(tg, j, 64));

    // Phase B: re-derive surviving chunks only; append survivors to shared buffer.
#pragma unroll
    for (int k = 0; k < 20; ++k) {
      if (chm[k] >= tg) {
        int c = lane + 64 * k;      // chm >= tg implies chunk was valid
        float4 A4 = A4p[c];
        float4 L4 = L4p[c];
        float ax, ay, az, aw_;
        if (ws_big) { ax = A4.x; ay = A4.y; az = A4.z; aw_ = A4.w; }
        else {
          ax  = __fmul_rn(WASR, __fsub_rn(__fsub_rn(A4.x, am), als));
          ay  = __fmul_rn(WASR, __fsub_rn(__fsub_rn(A4.y, am), als));
          az  = __fmul_rn(WASR, __fsub_rn(__fsub_rn(A4.z, am), als));
          aw_ = __fmul_rn(WASR, __fsub_rn(__fsub_rn(A4.w, am), als));
        }
        float vx = __fadd_rn(__fadd_rn(s, ax),  __fmul_rn(WLM, __fsub_rn(__fsub_rn(L4.x, mB), lsB)));
        float vy = __fadd_rn(__fadd_rn(s, ay),  __fmul_rn(WLM, __fsub_rn(__fsub_rn(L4.y, mB), lsB)));
        float vz = __fadd_rn(__fadd_rn(s, az),  __fmul_rn(WLM, __fsub_rn(__fsub_rn(L4.z, mB), lsB)));
        float vw = __fadd_rn(__fadd_rn(s, aw_), __fmul_rn(WLM, __fsub_rn(__fsub_rn(L4.w, mB), lsB)));
        int vb = c * 4;
        if (vx >= tg) { int p = atomicAdd(&s_cnt, 1); if (p < CAP) { s_bufval[p] = vx; s_bufidx[p] = w * VV + vb + 0; } }
        if (vy >= tg) { int p = atomicAdd(&s_cnt, 1); if (p < CAP) { s_bufval[p] = vy; s_bufidx[p] = w * VV + vb + 1; } }
        if (vz >= tg) { int p = atomicAdd(&s_cnt, 1); if (p < CAP) { s_bufval[p] = vz; s_bufidx[p] = w * VV + vb + 2; } }
        if (vw >= tg) { int p = atomicAdd(&s_cnt, 1); if (p < CAP) { s_bufval[p] = vw; s_bufidx[p] = w * VV + vb + 3; } }
      }
    }
    __syncthreads();

    // Phase C+D (wave 0): exact top-16 of survivors with (val desc, flat idx asc) order.
    if (w == 0) {
      int n = s_cnt; if (n > CAP) n = CAP;
      if (n <= 64) {
        float bv = (lane < n) ? s_bufval[lane] : -INFINITY;
        int   bi = (lane < n) ? s_bufidx[lane] : 0x7FFFFFFF;
#pragma unroll
        for (int kk = 2; kk <= 64; kk <<= 1) {
#pragma unroll
          for (int j = kk >> 1; j > 0; j >>= 1) {
            float ov = __shfl_xor(bv, j, 64);
            int   oi = __shfl_xor(bi, j, 64);
            bool keepTop = (((lane & kk) == 0) == ((lane & j) == 0));
            bool mineBetter = (bv > ov) || (bv == ov && bi < oi);
            bool takeOther = (keepTop != mineBetter);
            if (takeOther) { bv = ov; bi = oi; }
          }
        }
        if (lane < BEAMW) {
          float val = bv; int flat = bi;
          int bb  = flat / VV;
          int tok = flat - bb * VV;
          s_scores[lane] = val;
          s_last[lane]   = tok;
          s_lmm[lane]    = ws[OFF_LMM + tok];
          s_lmls[lane]   = ws[OFF_LMLS + tok];
          s_toks[t * BEAMW + lane] = (unsigned short)tok;
          s_bps[t * BEAMW + lane]  = (unsigned char)bb;
        }
      } else {
        // rare path: iterative extraction over up to CAP survivors
        float pv = -INFINITY; int pi = 0x7FFFFFFF;
        for (int it = 0; it < BEAMW; ++it) {
          float cv = -INFINITY; int ci = 0x7FFFFFFF;
          for (int k = 0; k < CAP / 64; ++k) {
            int p = lane + 64 * k;
            if (p < n) {
              float vv = s_bufval[p]; int ii = s_bufidx[p];
              bool lessPrev = (it == 0) || (vv < pv) || (vv == pv && ii > pi);
              bool better   = (vv > cv) || (vv == cv && ii < ci);
              if (lessPrev && better) { cv = vv; ci = ii; }
            }
          }
          for (int j = 1; j < 64; j <<= 1) {
            float ov = __shfl_xor(cv, j, 64); int oi = __shfl_xor(ci, j, 64);
            bool otherBetter = (ov > cv) || (ov == cv && oi < ci);
            if (otherBetter) { cv = ov; ci = oi; }
          }
          if (lane == it) {
            int bb  = ci / VV;
            int tok = ci - bb * VV;
            s_scores[it] = cv;
            s_last[it]   = tok;
            s_lmm[it]    = ws[OFF_LMM + tok];
            s_lmls[it]   = ws[OFF_LMLS + tok];
            s_toks[t * BEAMW + it] = (unsigned short)tok;
            s_bps[t * BEAMW + it]  = (unsigned char)bb;
          }
          pv = cv; pi = ci;
        }
      }
    }
    __syncthreads();
  }

  // Outputs: scores [16] then yseq [16][256] (as float).
  if (tid < BEAMW) {
    out[tid] = s_scores[tid];
    int ptr = tid;
    for (int t = TT - 1; t >= 0; --t) {
      int tok = (int)s_toks[t * BEAMW + ptr];
      out[BEAMW + tid * TT + t] = (float)tok;
      ptr = (int)s_bps[t * BEAMW + ptr];
    }
  }
}

extern "C" void kernel_launch(void* const* d_in, const int* in_sizes, int n_in,
                              void* d_out, int out_size, void* d_ws, size_t ws_size,
                              hipStream_t stream) {
  const float* asr = (const float*)d_in[0];
  const float* lm  = (const float*)d_in[1];
  float* out = (float*)d_out;
  float* ws  = (float*)d_ws;
  int ws_big = (ws_size >= (size_t)WS_NEED_FLOATS * sizeof(float)) ? 1 : 0;
  hipLaunchKernelGGL(prep_kernel, dim3(VV + TT), dim3(256), 0, stream, asr, lm, ws, ws_big);
  hipLaunchKernelGGL(beam_kernel, dim3(1), dim3(1024), 0, stream, asr, lm, ws, out, ws_big);
}

// Round 2
// 2682.837 us; speedup vs baseline: 4.9139x; 4.9139x over previous
//
#include <hip/hip_runtime.h>

#define TT 256         // time steps
#define VV 5000        // vocab
#define NC4 1250       // VV/4 float4 chunks per row
#define BEAMW 16
#define WASR 0.7f
#define WLM 0.3f
#define SOS_TOK 1
#define CAP 512
#define LK 96          // shortlist capacity per row
#define LTARGET 72     // histogram cumulative target for threshold

// ws float offsets
#define OFF_LMM   0                        // lm row max            [5000]
#define OFF_LMLS  5000                     // lm row log-sum-exp    [5000]
#define OFF_AM    10000                    // asr row max           [256]
#define OFF_ALS   10256                    // asr row logS          [256]
#define OFF_LMTH  10512                    // lm raw threshold      [5000] (+INF if overflow)
#define OFF_ATH   15512                    // asr raw threshold     [256]
#define OFF_LMBND 15768                    // lm scaled excl bound  [5000] (+INF if overflow)
#define OFF_ABND  20768                    // asr scaled excl bound [256]
#define OFF_LLIST 21024                    // float2 [5000][LK]
#define OFF_ALIST (OFF_LLIST + 2*VV*LK)    // float2 [256][LK]
#define WS_NEED_FLOATS (OFF_ALIST + 2*TT*LK)

// ---------------- prep: row max / logsumexp + top-shortlists ----------
__global__ __launch_bounds__(256) void prep_kernel(
    const float* __restrict__ asr, const float* __restrict__ lm,
    float* __restrict__ ws, int build_lists)
{
  __shared__ float sm[8];
  __shared__ int   hist[256];
  __shared__ float s_theta;
  __shared__ int   s_cnt;
  const int row = blockIdx.x;
  const bool is_lm = (row < VV);
  const int t = row - VV;
  const float* src = is_lm ? (lm + (size_t)row * VV) : (asr + (size_t)t * VV);
  const float4* s4 = (const float4*)src;

  float4 x[5];
  float m = -INFINITY;
#pragma unroll
  for (int k = 0; k < 5; ++k) {
    int c = (int)threadIdx.x + 256 * k;
    if (c < NC4) {
      x[k] = s4[c];
      m = fmaxf(m, fmaxf(fmaxf(x[k].x, x[k].y), fmaxf(x[k].z, x[k].w)));
    }
  }
#pragma unroll
  for (int j = 1; j < 64; j <<= 1) m = fmaxf(m, __shfl_xor(m, j, 64));
  if ((threadIdx.x & 63) == 0) sm[threadIdx.x >> 6] = m;
  __syncthreads();
  m = fmaxf(fmaxf(sm[0], sm[1]), fmaxf(sm[2], sm[3]));
  __syncthreads();

  float ssum = 0.f;
#pragma unroll
  for (int k = 0; k < 5; ++k) {
    int c = (int)threadIdx.x + 256 * k;
    if (c < NC4) {
      ssum += expf(x[k].x - m);
      ssum += expf(x[k].y - m);
      ssum += expf(x[k].z - m);
      ssum += expf(x[k].w - m);
    }
  }
#pragma unroll
  for (int j = 1; j < 64; j <<= 1) ssum += __shfl_xor(ssum, j, 64);
  if ((threadIdx.x & 63) == 0) sm[4 + (threadIdx.x >> 6)] = ssum;
  __syncthreads();
  ssum = (sm[4] + sm[5]) + (sm[6] + sm[7]);
  const float logS = logf(ssum);

  if (threadIdx.x == 0) {
    if (is_lm) { ws[OFF_LMM + row] = m; ws[OFF_LMLS + row] = logS; }
    else       { ws[OFF_AM + t]   = m; ws[OFF_ALS + t]   = logS; }
  }
  if (!build_lists) return;

  // ---- histogram of y = m - x, 256 bins of width 1/16 ----
  hist[threadIdx.x] = 0;
  __syncthreads();
#pragma unroll
  for (int k = 0; k < 5; ++k) {
    int c = (int)threadIdx.x + 256 * k;
    if (c < NC4) {
      float vv[4] = {x[k].x, x[k].y, x[k].z, x[k].w};
#pragma unroll
      for (int j = 0; j < 4; ++j) {
        float y = m - vv[j];
        int b = (int)(y * 16.0f);
        b = b < 0 ? 0 : (b > 255 ? 255 : b);
        atomicAdd(&hist[b], 1);
      }
    }
  }
  __syncthreads();
  if (threadIdx.x == 0) {
    int c = 0, b = 0;
    for (; b < 255; ++b) { c += hist[b]; if (c >= LTARGET) break; }
    s_theta = m - (float)(b + 1) * 0.0625f;
    s_cnt = 0;
  }
  __syncthreads();
  const float theta = s_theta;
  const float wgt = is_lm ? WLM : WASR;
  float2* dst = is_lm ? ((float2*)(ws + OFF_LLIST) + (size_t)row * LK)
                      : ((float2*)(ws + OFF_ALIST) + (size_t)t * LK);
#pragma unroll
  for (int k = 0; k < 5; ++k) {
    int c = (int)threadIdx.x + 256 * k;
    if (c < NC4) {
      float vv[4] = {x[k].x, x[k].y, x[k].z, x[k].w};
#pragma unroll
      for (int j = 0; j < 4; ++j) {
        float xv = vv[j];
        if (xv >= theta) {
          int p = atomicAdd(&s_cnt, 1);
          if (p < LK) {
            float sv = __fmul_rn(wgt, __fsub_rn(__fsub_rn(xv, m), logS));
            dst[p] = make_float2(sv, __int_as_float(c * 4 + j));
          }
        }
      }
    }
  }
  __syncthreads();
  const int cnt = s_cnt;
  const bool ovf = (cnt > LK);
  if (!ovf) {
    for (int p = cnt + (int)threadIdx.x; p < LK; p += 256)
      dst[p] = make_float2(-1e30f, __int_as_float(0));
  } else {
    // truncated list is unusable for exclusion bounds: wipe & mark infinite
    for (int p = (int)threadIdx.x; p < LK; p += 256)
      dst[p] = make_float2(-1e30f, __int_as_float(0));
  }
  if (threadIdx.x == 0) {
    float bnd = ovf ? INFINITY : __fmul_rn(wgt, __fsub_rn(__fsub_rn(theta, m), logS));
    float thO = ovf ? INFINITY : theta;
    if (is_lm) { ws[OFF_LMTH + row] = thO; ws[OFF_LMBND + row] = bnd; }
    else       { ws[OFF_ATH + t]   = thO; ws[OFF_ABND + t]   = bnd; }
  }
}

// ---------------- sort helpers ----------------
__device__ __forceinline__ float bitonic64_desc_val(float v, int lane) {
#pragma unroll
  for (int kk = 2; kk <= 64; kk <<= 1)
#pragma unroll
    for (int j = kk >> 1; j > 0; j >>= 1) {
      float o = __shfl_xor(v, j, 64);
      bool keepMax = (((lane & kk) == 0) == ((lane & j) == 0));
      v = keepMax ? fmaxf(v, o) : fminf(v, o);
    }
  return v;
}

__device__ __forceinline__ void bitonic64_desc_pair(float& bv, int& bi, int lane) {
#pragma unroll
  for (int kk = 2; kk <= 64; kk <<= 1)
#pragma unroll
    for (int j = kk >> 1; j > 0; j >>= 1) {
      float ov = __shfl_xor(bv, j, 64);
      int   oi = __shfl_xor(bi, j, 64);
      bool keepTop = (((lane & kk) == 0) == ((lane & j) == 0));
      bool mineBetter = (bv > ov) || (bv == ov && bi < oi);
      if (keepTop != mineBetter) { bv = ov; bi = oi; }
    }
}

__device__ __forceinline__ float cand_val(float s, float a, float am, float als,
                                          float x, float mB, float lsB) {
  float av = __fmul_rn(WASR, __fsub_rn(__fsub_rn(a, am), als));
  float lv = __fmul_rn(WLM,  __fsub_rn(__fsub_rn(x, mB), lsB));
  return __fadd_rn(__fadd_rn(s, av), lv);
}

// ---------------- fast beam kernel: shortlist candidates + exact bound check ----
__global__ __launch_bounds__(1024, 4) void beam_fast(
    const float* __restrict__ asr, const float* __restrict__ lm,
    const float* __restrict__ ws, float* __restrict__ out)
{
  __shared__ float s_scores[BEAMW];
  __shared__ int   s_last[BEAMW];
  __shared__ float s_lmm[BEAMW], s_lmls[BEAMW], s_lth[BEAMW], s_lbnd[BEAMW];
  __shared__ float s_am[TT], s_als[TT], s_ath[TT], s_abnd[TT];
  __shared__ float s_mrg[BEAMW][BEAMW + 1];
  __shared__ float s_m2v[4][BEAMW];
  __shared__ int   s_m2i[4][BEAMW];
  __shared__ float s_bound[BEAMW];
  __shared__ float s_bufval[CAP];
  __shared__ int   s_bufidx[CAP];
  __shared__ int   s_cnt;
  __shared__ int   s_flags;
  __shared__ float s_selv[BEAMW];
  __shared__ int   s_seli[BEAMW];
  __shared__ float s_tau16;
  __shared__ unsigned short s_toks[TT * BEAMW];
  __shared__ unsigned char  s_bps[TT * BEAMW];

  const int tid = (int)threadIdx.x;
  const int lane = tid & 63;
  const int w = tid >> 6;

  if (tid < TT) {
    s_am[tid]   = ws[OFF_AM + tid];
    s_als[tid]  = ws[OFF_ALS + tid];
    s_ath[tid]  = ws[OFF_ATH + tid];
    s_abnd[tid] = ws[OFF_ABND + tid];
  }
  if (tid < BEAMW) {
    s_scores[tid] = (tid == 0) ? 0.0f : -1e30f;
    s_last[tid]   = SOS_TOK;
    s_lmm[tid]  = ws[OFF_LMM + SOS_TOK];
    s_lmls[tid] = ws[OFF_LMLS + SOS_TOK];
    s_lth[tid]  = ws[OFF_LMTH + SOS_TOK];
    s_lbnd[tid] = ws[OFF_LMBND + SOS_TOK];
  }
  __syncthreads();

  for (int t = 0; t < TT; ++t) {
    const float s = s_scores[w];
    const int last = s_last[w];
    const float mB = s_lmm[w], lsB = s_lmls[w], thL = s_lth[w];
    const float am = s_am[t], als = s_als[t], thA = s_ath[t];
    const float2* __restrict__ Al = (const float2*)(ws + OFF_ALIST) + (size_t)t * LK;
    const float2* __restrict__ Ll = (const float2*)(ws + OFF_LLIST) + (size_t)last * LK;

    if (tid == 0) { s_cnt = 0; s_flags = 0; }
    if (lane == 0) s_bound[w] = __fadd_rn(__fadd_rn(s, s_abnd[t]), s_lbnd[w]) + 1e-3f;

    // ---- candidate slots: 2 from A-list, 2 from L-list ----
    float cv[4]; int ctk[4];
#pragma unroll
    for (int r = 0; r < 2; ++r) {
      int j = lane + 64 * r;
      float v = -INFINITY; int tok = 0;
      if (j < LK) {
        float2 e = Al[j];
        tok = __float_as_int(e.y);
        float av = e.x;
        if (av > -9e29f) {
          float xr = lm[(size_t)last * VV + tok];
          if (!(xr >= thL)) {                 // dedupe: token also in L-list
            float lv = __fmul_rn(WLM, __fsub_rn(__fsub_rn(xr, mB), lsB));
            v = __fadd_rn(__fadd_rn(s, av), lv);
          }
        }
      }
      cv[r] = v; ctk[r] = tok;
    }
#pragma unroll
    for (int r = 0; r < 2; ++r) {
      int j = lane + 64 * r;
      float v = -INFINITY; int tok = 0;
      if (j < LK) {
        float2 e = Ll[j];
        tok = __float_as_int(e.y);
        float lv = e.x;
        if (lv > -9e29f) {
          float ar = asr[(size_t)t * VV + tok];
          float av = __fmul_rn(WASR, __fsub_rn(__fsub_rn(ar, am), als));
          v = __fadd_rn(__fadd_rn(s, av), lv);
        }
      }
      cv[2 + r] = v; ctk[2 + r] = tok;
    }

    // ---- per-wave sorted lane-maxes, then 4-round merge -> global 16th lane-max ----
    float lmax = fmaxf(fmaxf(cv[0], cv[1]), fmaxf(cv[2], cv[3]));
    float vs = bitonic64_desc_val(lmax, lane);
    if (lane < 16) s_mrg[w][lane] = vs;
    __syncthreads();
#pragma unroll
    for (int rd = 0; rd < 4; ++rd) {
      int nm = 8 >> rd;
      if (w < nm) {
        int stepw = 2 << rd;
        int la = w * stepw, lb = la + (stepw >> 1);
        if (lane < 32) {
          float v = (lane < 16) ? s_mrg[la][lane] : s_mrg[lb][31 - lane];
#pragma unroll
          for (int j = 16; j > 0; j >>= 1) {
            float o = __shfl_xor(v, j, 64);
            v = ((lane & j) == 0) ? fmaxf(v, o) : fminf(v, o);
          }
          if (lane < 16) s_mrg[la][lane] = v;
        }
      }
      __syncthreads();
    }
    const float tg = s_mrg[0][15];   // >=16 real elements are >= tg

    // ---- append survivors ----
#pragma unroll
    for (int k = 0; k < 4; ++k) {
      if (cv[k] >= tg && cv[k] >= -3.0e38f) {
        int p = atomicAdd(&s_cnt, 1);
        if (p < CAP) { s_bufval[p] = cv[k]; s_bufidx[p] = w * VV + ctk[k]; }
      }
    }
    __syncthreads();

    int n = s_cnt;
    bool fullredo = (n > CAP);

    // ---- exact top-16 selection over the pool (uniform control flow) ----
    auto select16 = [&](int nn) {
      if (nn <= 64) {
        if (w == 0) {
          float bv = (lane < nn) ? s_bufval[lane] : -INFINITY;
          int   bi = (lane < nn) ? s_bufidx[lane] : 0x7FFFFFFF;
          bitonic64_desc_pair(bv, bi, lane);
          if (lane < 16) { s_selv[lane] = bv; s_seli[lane] = bi; }
          if (lane == 15) s_tau16 = bv;
        }
      } else if (nn <= 256) {
        if (w < 4) {
          int p = (w << 6) + lane;
          float bv = (p < nn) ? s_bufval[p] : -INFINITY;
          int   bi = (p < nn) ? s_bufidx[p] : 0x7FFFFFFF;
          bitonic64_desc_pair(bv, bi, lane);
          if (lane < 16) { s_m2v[w][lane] = bv; s_m2i[w][lane] = bi; }
        }
        __syncthreads();
        if (w == 0) {
          float bv = s_m2v[lane >> 4][lane & 15];
          int   bi = s_m2i[lane >> 4][lane & 15];
          bitonic64_desc_pair(bv, bi, lane);
          if (lane < 16) { s_selv[lane] = bv; s_seli[lane] = bi; }
          if (lane == 15) s_tau16 = bv;
        }
      } else {
        if (w == 0) {
          float pv = -INFINITY; int pi = 0x7FFFFFFF;
          for (int it = 0; it < BEAMW; ++it) {
            float cvv = -INFINITY; int cii = 0x7FFFFFFF;
            for (int k2 = 0; k2 < CAP / 64; ++k2) {
              int p = lane + (k2 << 6);
              if (p < nn) {
                float vv2 = s_bufval[p]; int ii2 = s_bufidx[p];
                bool lessPrev = (it == 0) || (vv2 < pv) || (vv2 == pv && ii2 > pi);
                bool better = (vv2 > cvv) || (vv2 == cvv && ii2 < cii);
                if (lessPrev && better) { cvv = vv2; cii = ii2; }
              }
            }
            for (int j = 1; j < 64; j <<= 1) {
              float ov = __shfl_xor(cvv, j, 64); int oi = __shfl_xor(cii, j, 64);
              bool ob = (ov > cvv) || (ov == cvv && oi < cii);
              if (ob) { cvv = ov; cii = oi; }
            }
            if (lane == 0) { s_selv[it] = cvv; s_seli[it] = cii; if (it == 15) s_tau16 = cvv; }
            pv = cvv; pi = cii;
          }
        }
      }
      __syncthreads();
    };

    if (!fullredo) {
      select16(n);
      // exclusion-bound check per row
      if (lane == 0 && s_bound[w] > s_tau16) atomicOr(&s_flags, (1 << w));
      __syncthreads();
      int fl = s_flags;
      if (fl) {
        const float tau = s_tau16;     // tau >= tg, so pool membership == inlist for v>=tau
        for (int b = 0; b < BEAMW; ++b) {
          if (!((fl >> b) & 1)) continue;
          float sb = s_scores[b];
          int lastb = s_last[b];
          float mBb = s_lmm[b], lsBb = s_lmls[b], thLb = s_lth[b];
          const float4* A4 = (const float4*)(asr + (size_t)t * VV);
          const float4* L4 = (const float4*)(lm + (size_t)lastb * VV);
          for (int c = tid; c < NC4; c += 1024) {
            float4 a4 = A4[c]; float4 l4 = L4[c];
            float ar4[4] = {a4.x, a4.y, a4.z, a4.w};
            float lr4[4] = {l4.x, l4.y, l4.z, l4.w};
#pragma unroll
            for (int i = 0; i < 4; ++i) {
              float v = cand_val(sb, ar4[i], am, als, lr4[i], mBb, lsBb);
              bool inlist = (ar4[i] >= thA) || (lr4[i] >= thLb);
              if (v >= tau && !inlist) {
                int p = atomicAdd(&s_cnt, 1);
                if (p < CAP) { s_bufval[p] = v; s_bufidx[p] = b * VV + c * 4 + i; }
              }
            }
          }
        }
        __syncthreads();
        n = s_cnt;
        if (n > CAP) fullredo = true;
        else select16(n);
      }
    }

    if (fullredo) {
      // exact full scan of all 16 rows (round-1 machinery)
      if (tid == 0) s_cnt = 0;
      __syncthreads();
      const float4* A4p = (const float4*)(asr + (size_t)t * VV);
      const float4* L4p = (const float4*)(lm + (size_t)last * VV);
      float chm[20]; float rowm = -INFINITY;
#pragma unroll
      for (int k = 0; k < 20; ++k) {
        int c = lane + (k << 6);
        bool ok = (c < NC4);
        int cc = ok ? c : 0;
        float4 a4 = A4p[cc]; float4 l4 = L4p[cc];
        float vx = cand_val(s, a4.x, am, als, l4.x, mB, lsB);
        float vy = cand_val(s, a4.y, am, als, l4.y, mB, lsB);
        float vz = cand_val(s, a4.z, am, als, l4.z, mB, lsB);
        float vw = cand_val(s, a4.w, am, als, l4.w, mB, lsB);
        float cm = fmaxf(fmaxf(vx, vy), fmaxf(vz, vw));
        if (!ok) cm = -INFINITY;
        chm[k] = cm; rowm = fmaxf(rowm, cm);
      }
      float vsr = bitonic64_desc_val(rowm, lane);
      if (lane == 15) s_mrg[w][0] = vsr;
      __syncthreads();
      float tg2 = -INFINITY;
      for (int b = 0; b < BEAMW; ++b) tg2 = fmaxf(tg2, s_mrg[b][0]);
#pragma unroll
      for (int k = 0; k < 20; ++k) {
        if (chm[k] >= tg2) {
          int c = lane + (k << 6);
          float4 a4 = A4p[c]; float4 l4 = L4p[c];
          float ar4[4] = {a4.x, a4.y, a4.z, a4.w};
          float lr4[4] = {l4.x, l4.y, l4.z, l4.w};
#pragma unroll
          for (int i = 0; i < 4; ++i) {
            float v = cand_val(s, ar4[i], am, als, lr4[i], mB, lsB);
            if (v >= tg2) {
              int p = atomicAdd(&s_cnt, 1);
              if (p < CAP) { s_bufval[p] = v; s_bufidx[p] = w * VV + c * 4 + i; }
            }
          }
        }
      }
      __syncthreads();
      int n2 = s_cnt; if (n2 > CAP) n2 = CAP;
      select16(n2);
    }

    // ---- commit ----
    if (w == 0 && lane < BEAMW) {
      float val = s_selv[lane]; int flat = s_seli[lane];
      int bb = flat / VV;
      int tok = flat - bb * VV;
      s_scores[lane] = val;
      s_last[lane] = tok;
      s_lmm[lane]  = ws[OFF_LMM + tok];
      s_lmls[lane] = ws[OFF_LMLS + tok];
      s_lth[lane]  = ws[OFF_LMTH + tok];
      s_lbnd[lane] = ws[OFF_LMBND + tok];
      s_toks[t * BEAMW + lane] = (unsigned short)tok;
      s_bps[t * BEAMW + lane]  = (unsigned char)bb;
    }
    __syncthreads();
  }

  if (tid < BEAMW) {
    out[tid] = s_scores[tid];
    int ptr = tid;
    for (int t = TT - 1; t >= 0; --t) {
      int tok = (int)s_toks[t * BEAMW + ptr];
      out[BEAMW + tid * TT + t] = (float)tok;
      ptr = (int)s_bps[t * BEAMW + ptr];
    }
  }
}

// ---------------- fallback: round-1 full-scan kernel (ws too small for lists) ----
__global__ __launch_bounds__(1024, 4) void beam_slow(
    const float* __restrict__ asr, const float* __restrict__ lm,
    const float* __restrict__ ws, float* __restrict__ out)
{
  __shared__ float s_scores[BEAMW];
  __shared__ int   s_last[BEAMW];
  __shared__ float s_lmm[BEAMW], s_lmls[BEAMW];
  __shared__ float s_tau[BEAMW];
  __shared__ float s_bufval[CAP];
  __shared__ int   s_bufidx[CAP];
  __shared__ int   s_cnt;
  __shared__ unsigned short s_toks[TT * BEAMW];
  __shared__ unsigned char  s_bps[TT * BEAMW];

  const int tid = (int)threadIdx.x;
  const int lane = tid & 63;
  const int w = tid >> 6;

  if (tid < BEAMW) {
    s_scores[tid] = (tid == 0) ? 0.0f : -1e30f;
    s_last[tid] = SOS_TOK;
    s_lmm[tid] = ws[OFF_LMM + SOS_TOK];
    s_lmls[tid] = ws[OFF_LMLS + SOS_TOK];
  }
  if (tid == 0) s_cnt = 0;
  __syncthreads();

  for (int t = 0; t < TT; ++t) {
    const float s = s_scores[w];
    const float mB = s_lmm[w], lsB = s_lmls[w];
    const int lastb = s_last[w];
    const float am = ws[OFF_AM + t], als = ws[OFF_ALS + t];
    const float4* __restrict__ L4p = (const float4*)(lm + (size_t)lastb * VV);
    const float4* __restrict__ A4p = (const float4*)(asr + (size_t)t * VV);

    float chm[20]; float rowm = -INFINITY;
#pragma unroll
    for (int k = 0; k < 20; ++k) {
      int c = lane + 64 * k;
      bool ok = (c < NC4);
      int cc = ok ? c : 0;
      float4 A4 = A4p[cc]; float4 L4 = L4p[cc];
      float vx = cand_val(s, A4.x, am, als, L4.x, mB, lsB);
      float vy = cand_val(s, A4.y, am, als, L4.y, mB, lsB);
      float vz = cand_val(s, A4.z, am, als, L4.z, mB, lsB);
      float vw = cand_val(s, A4.w, am, als, L4.w, mB, lsB);
      float cm = fmaxf(fmaxf(vx, vy), fmaxf(vz, vw));
      if (!ok) cm = -INFINITY;
      chm[k] = cm; rowm = fmaxf(rowm, cm);
    }
    {
      float v = bitonic64_desc_val(rowm, lane);
      if (lane == 15) s_tau[w] = v;
    }
    if (tid == 0) s_cnt = 0;
    __syncthreads();

    float tg = s_tau[lane & 15];
#pragma unroll
    for (int j = 1; j <= 8; j <<= 1) tg = fmaxf(tg, __shfl_xor(tg, j, 64));

#pragma unroll
    for (int k = 0; k < 20; ++k) {
      if (chm[k] >= tg) {
        int c = lane + 64 * k;
        float4 A4 = A4p[c]; float4 L4 = L4p[c];
        float ar4[4] = {A4.x, A4.y, A4.z, A4.w};
        float lr4[4] = {L4.x, L4.y, L4.z, L4.w};
#pragma unroll
        for (int i = 0; i < 4; ++i) {
          float v = cand_val(s, ar4[i], am, als, lr4[i], mB, lsB);
          if (v >= tg) {
            int p = atomicAdd(&s_cnt, 1);
            if (p < CAP) { s_bufval[p] = v; s_bufidx[p] = w * VV + c * 4 + i; }
          }
        }
      }
    }
    __syncthreads();

    if (w == 0) {
      int n = s_cnt; if (n > CAP) n = CAP;
      if (n <= 64) {
        float bv = (lane < n) ? s_bufval[lane] : -INFINITY;
        int   bi = (lane < n) ? s_bufidx[lane] : 0x7FFFFFFF;
        bitonic64_desc_pair(bv, bi, lane);
        if (lane < BEAMW) {
          int flat = bi;
          int bb = flat / VV; int tok = flat - bb * VV;
          s_scores[lane] = bv; s_last[lane] = tok;
          s_lmm[lane] = ws[OFF_LMM + tok]; s_lmls[lane] = ws[OFF_LMLS + tok];
          s_toks[t * BEAMW + lane] = (unsigned short)tok;
          s_bps[t * BEAMW + lane] = (unsigned char)bb;
        }
      } else {
        float pv = -INFINITY; int pi = 0x7FFFFFFF;
        for (int it = 0; it < BEAMW; ++it) {
          float cvv = -INFINITY; int cii = 0x7FFFFFFF;
          for (int k2 = 0; k2 < CAP / 64; ++k2) {
            int p = lane + 64 * k2;
            if (p < n) {
              float vv2 = s_bufval[p]; int ii2 = s_bufidx[p];
              bool lessPrev = (it == 0) || (vv2 < pv) || (vv2 == pv && ii2 > pi);
              bool better = (vv2 > cvv) || (vv2 == cvv && ii2 < cii);
              if (lessPrev && better) { cvv = vv2; cii = ii2; }
            }
          }
          for (int j = 1; j < 64; j <<= 1) {
            float ov = __shfl_xor(cvv, j, 64); int oi = __shfl_xor(cii, j, 64);
            bool ob = (ov > cvv) || (ov == cvv && oi < cii);
            if (ob) { cvv = ov; cii = oi; }
          }
          if (lane == 0) {
            int bb = cii / VV; int tok = cii - bb * VV;
            s_scores[it] = cvv; s_last[it] = tok;
            s_lmm[it] = ws[OFF_LMM + tok]; s_lmls[it] = ws[OFF_LMLS + tok];
            s_toks[t * BEAMW + it] = (unsigned short)tok;
            s_bps[t * BEAMW + it] = (unsigned char)bb;
          }
          pv = cvv; pi = cii;
        }
      }
    }
    __syncthreads();
  }

  if (tid < BEAMW) {
    out[tid] = s_scores[tid];
    int ptr = tid;
    for (int t = TT - 1; t >= 0; --t) {
      int tok = (int)s_toks[t * BEAMW + ptr];
      out[BEAMW + tid * TT + t] = (float)tok;
      ptr = (int)s_bps[t * BEAMW + ptr];
    }
  }
}

extern "C" void kernel_launch(void* const* d_in, const int* in_sizes, int n_in,
                              void* d_out, int out_size, void* d_ws, size_t ws_size,
                              hipStream_t stream) {
  const float* asr = (const float*)d_in[0];
  const float* lm  = (const float*)d_in[1];
  float* out = (float*)d_out;
  float* ws  = (float*)d_ws;
  int lists = (ws_size >= (size_t)WS_NEED_FLOATS * sizeof(float)) ? 1 : 0;
  hipLaunchKernelGGL(prep_kernel, dim3(VV + TT), dim3(256), 0, stream, asr, lm, ws, lists);
  if (lists)
    hipLaunchKernelGGL(beam_fast, dim3(1), dim3(1024), 0, stream, asr, lm, ws, out);
  else
    hipLaunchKernelGGL(beam_slow, dim3(1), dim3(1024), 0, stream, asr, lm, ws, out);
}